// Round 12
// baseline (257.028 us; speedup 1.0000x reference)
//
#include <hip/hip_runtime.h>
#include <math.h>

#define N_NODES 50000
#define N_EDGES 800000
#define DIM 128
#define NEG_SLOPE 0.01f
#define CAP 64    // per-node slot capacity; P(deg>64)~5e-15 for Poisson(16)
#define DEGS 32   // deg counter stride (ints): 1 counter per 128B line

#define GEMM_BLOCKS 3125   // 50000/16 rows, exact
#define SCAT_BLOCKS 3125   // 800000/256 edges, exact

typedef short v8s __attribute__((ext_vector_type(8)));
typedef float v4f __attribute__((ext_vector_type(4)));

// ---- bf16 helpers (RNE) ---------------------------------------------------
__device__ inline unsigned f2bf2(float a, float b) {
    unsigned ua = __float_as_uint(a);
    unsigned ub = __float_as_uint(b);
    ua = (ua + 0x7fffu + ((ua >> 16) & 1u)) >> 16;
    ub = (ub + 0x7fffu + ((ub >> 16) & 1u)) & 0xffff0000u;
    return ua | ub;
}
__device__ inline float2 bf2f(unsigned u) {
    float2 r;
    r.x = __uint_as_float(u << 16);
    r.y = __uint_as_float(u & 0xffff0000u);
    return r;
}

// ---- packed-f32-shaped helpers -------------------------------------------
__device__ inline float2 pka(float2 a, float2 b) {
    return make_float2(a.x + b.x, a.y + b.y);
}
__device__ inline float2 pkfma(float2 a, float2 b, float2 c) {
    return make_float2(fmaf(a.x, b.x, c.x), fmaf(a.y, b.y, c.y));
}
// leaky_relu(v) == max(v, slope*v) exactly, for 0 < slope < 1
__device__ inline float2 leaky2(float2 v) {
    return make_float2(fmaxf(v.x, v.x * NEG_SLOPE), fmaxf(v.y, v.y * NEG_SLOPE));
}

// VALU-forwarded 16-lane sum via DPP row rotations. Executed only when the
// owning 16-lane row is fully active (validity is row-uniform).
#define ROR_ADD(v, CTRL) \
    ((v) + __int_as_float(__builtin_amdgcn_update_dpp( \
        0, __float_as_int(v), (CTRL), 0xf, 0xf, false)))

// ---------------------------------------------------------------------------
// Prep: weights -> whT bf16 (n-major, k-pair-contiguous) + zero deg counters
// (one word per 128B line).
// ---------------------------------------------------------------------------
__global__ __launch_bounds__(256) void k_prepw(
    const float* __restrict__ src_w, const float* __restrict__ dst_w,
    unsigned* __restrict__ whT, int* __restrict__ deg)
{
    int gid = blockIdx.x * 256 + threadIdx.x;   // 256 blocks -> 65536 threads
    if (gid < 256 * 64) {
        int n = gid >> 6;
        int kk = gid & 63;
        const float* W = (n < 128) ? src_w : dst_w;
        int col = n & 127;
        float w0 = W[(2 * kk) * DIM + col];
        float w1 = W[(2 * kk + 1) * DIM + col];
        whT[gid] = f2bf2(w0, w1);
    }
    if (gid < N_NODES) deg[gid * DEGS] = 0;
}

// ---------------------------------------------------------------------------
// Standalone scatter: zero LDS, 1 edge/thread, full occupancy ceiling
// (32 waves/CU) -> maximal atomic parallelism. Padded deg counters.
// ---------------------------------------------------------------------------
__global__ __launch_bounds__(256) void k_scatter(
    const int* __restrict__ src, const int* __restrict__ dst,
    int* __restrict__ deg, int* __restrict__ slots)
{
    int e = blockIdx.x * 256 + threadIdx.x;   // exact: 3125*256 == 800000
    int s = src[e];
    int d = dst[e];
    int pos = atomicAdd(&deg[d * DEGS], 1);
    if (pos < CAP) slots[d * CAP + pos] = s * 64;
}

// ---------------------------------------------------------------------------
// Standalone GEMM, 1-wave blocks (16 rows each, exact tiling, barrier-free).
// ---------------------------------------------------------------------------
__global__ __launch_bounds__(64) void k_gemm(
    const float* __restrict__ x, const unsigned* __restrict__ whT,
    const float* __restrict__ src_b, unsigned* __restrict__ hx_u,
    unsigned* __restrict__ yu)
{
    __shared__ unsigned L[16][132];   // 8448 B; rows 16B-aligned, stride%32=4
    int bx = blockIdx.x;
    int lane = threadIdx.x;
    int quad = lane >> 4;
    int m = lane & 15;

    // ---- x staging loads (8 x float4; no guards, exact tiling) -------------
    int arow = bx * 16 + m;
    const float4* xp = (const float4*)(x + (size_t)arow * DIM + quad * 8);
    float4 f[4][2];
    #pragma unroll
    for (int k0 = 0; k0 < 4; ++k0) {
        f[k0][0] = xp[k0 * 8];
        f[k0][1] = xp[k0 * 8 + 1];
    }

    // ---- pack -> b[] + LDS -------------------------------------------------
    v8s b[4];
    #pragma unroll
    for (int k0 = 0; k0 < 4; ++k0) {
        union { unsigned u[4]; v8s s; } pk;
        pk.u[0] = f2bf2(f[k0][0].x, f[k0][0].y);
        pk.u[1] = f2bf2(f[k0][0].z, f[k0][0].w);
        pk.u[2] = f2bf2(f[k0][1].x, f[k0][1].y);
        pk.u[3] = f2bf2(f[k0][1].z, f[k0][1].w);
        b[k0] = pk.s;
        int c = k0 * 32 + quad * 8 + 1;          // x-pairs at odd columns
        L[m][c + 0] = pk.u[0];
        L[m][c + 2] = pk.u[1];
        L[m][c + 4] = pk.u[2];
        L[m][c + 6] = pk.u[3];
    }

    // ---- MFMA loop ---------------------------------------------------------
    v4f yacc[8];
    #pragma unroll
    for (int nt = 0; nt < 16; ++nt) {
        v4f acc = {0.f, 0.f, 0.f, 0.f};
        const uint4* ap = (const uint4*)(whT + (size_t)(nt * 16 + m) * 64 + quad * 4);
        #pragma unroll
        for (int k0 = 0; k0 < 4; ++k0) {
            union { uint4 u; v8s s; } af;
            af.u = ap[k0 * 4];
            acc = __builtin_amdgcn_mfma_f32_16x16x32_bf16(af.s, b[k0], acc, 0, 0, 0);
        }
        if (nt < 8) {                            // ha_src pairs at even cols
            float4 bia = ((const float4*)src_b)[nt * 4 + quad];
            int c = nt * 16 + quad * 4;
            L[m][c]     = f2bf2(acc[0] + bia.x, acc[1] + bia.y);
            L[m][c + 2] = f2bf2(acc[2] + bia.z, acc[3] + bia.w);
        } else {
            yacc[nt - 8] = acc;
        }
    }

    // ---- store hx (wave-private LDS; no barrier, no guards) ----------------
    int rbase0 = bx * 16;
    for (int i = lane; i < 512; i += 64) {
        int r = i >> 5, c = i & 31;
        ((uint4*)(hx_u + (size_t)(rbase0 + r) * 128))[c] = *(const uint4*)&L[r][c * 4];
    }

    // ---- stage yu into cols 0..63 of same buffer, store --------------------
    #pragma unroll
    for (int t = 0; t < 8; ++t) {
        int c = t * 8 + quad * 2;
        L[m][c]     = f2bf2(yacc[t][0], yacc[t][1]);
        L[m][c + 1] = f2bf2(yacc[t][2], yacc[t][3]);
    }
    for (int i = lane; i < 256; i += 64) {
        int r = i >> 4, c = i & 15;
        ((uint4*)(yu + (size_t)(rbase0 + r) * 64))[c] = *(const uint4*)&L[r][c * 4];
    }
}

// ---------------------------------------------------------------------------
// Pass 1 standalone: hd = mean(y[src]) + dst_b, written as bf16 pairs.
// Gather working set is yu alone (12.8 MB) -> better L2 behavior than the
// interleaved yu+hx mix. 4 groups x 16 lanes, dense uint2 gathers,
// uniform-trip + all-lane shfl broadcast discipline.
// ---------------------------------------------------------------------------
__global__ __launch_bounds__(256) void k_mean(
    const unsigned* __restrict__ yu, const int* __restrict__ slots,
    const int* __restrict__ deg, const float* __restrict__ dst_b,
    unsigned* __restrict__ hdu)
{
    int g = blockIdx.x * 256 + threadIdx.x;
    int node = g >> 6;
    int lane = g & 63;
    int grp = lane >> 4;
    int sl = lane & 15;
    int cnt = deg[node * DEGS];
    if (cnt == 0) return;                     // k_score's zero-path never reads hd
    int cc = (cnt < CAP) ? cnt : CAP;
    int trips = (cc + 3) >> 2;
    int myoff = (lane < cc) ? slots[node * CAP + lane] : 0;

    // lane sl owns pairs {2sl,2sl+1} and {32+2sl,32+2sl+1}
    float2 hd01 = {0.f, 0.f}, hd23 = {0.f, 0.f};
    float2 hd45 = {0.f, 0.f}, hd67 = {0.f, 0.f};
    #pragma unroll 4
    for (int t = 0; t < trips; ++t) {
        int i = 4 * t + grp;
        bool valid = (i < cc);
        int off = __shfl(myoff, valid ? i : 0);   // all lanes active here
        if (valid) {                              // row-uniform guard
            const uint2* yp = (const uint2*)(yu + off);
            uint2 qa = yp[sl];
            uint2 qb = yp[16 + sl];
            hd01 = pka(hd01, bf2f(qa.x));
            hd23 = pka(hd23, bf2f(qa.y));
            hd45 = pka(hd45, bf2f(qb.x));
            hd67 = pka(hd67, bf2f(qb.y));
        }
    }
    float inv = 1.0f / (float)cnt;
    #define XRED(f) { f += __shfl_xor(f, 32); f += __shfl_xor(f, 16); f *= inv; }
    XRED(hd01.x) XRED(hd01.y) XRED(hd23.x) XRED(hd23.y)
    XRED(hd45.x) XRED(hd45.y) XRED(hd67.x) XRED(hd67.y)
    #undef XRED
    float4 db0 = ((const float4*)dst_b)[sl];
    float4 db1 = ((const float4*)dst_b)[16 + sl];
    hd01.x += db0.x; hd01.y += db0.y; hd23.x += db0.z; hd23.y += db0.w;
    hd45.x += db1.x; hd45.y += db1.y; hd67.x += db1.z; hd67.y += db1.w;

    if (grp == 0) {
        uint2 w0 = make_uint2(f2bf2(hd01.x, hd01.y), f2bf2(hd23.x, hd23.y));
        ((uint2*)(hdu + (size_t)node * 64))[sl] = w0;
    } else if (grp == 1) {
        uint2 w1 = make_uint2(f2bf2(hd45.x, hd45.y), f2bf2(hd67.x, hd67.y));
        ((uint2*)(hdu + (size_t)node * 64))[16 + sl] = w1;
    }
}

// ---------------------------------------------------------------------------
// Pass 2 standalone: scores + softmax + weighted sum. Gather working set is
// hx alone (25.6 MB). hd loaded from hdu (bf16). Dense uint4 gathers,
// DPP row_ror score reduce, uniform-trip + all-lane shfl broadcast.
// ---------------------------------------------------------------------------
__global__ __launch_bounds__(256) void k_score(
    const uint2* __restrict__ hx, const unsigned* __restrict__ hdu,
    const int* __restrict__ slots, const int* __restrict__ deg,
    const float* __restrict__ att_w, const float* __restrict__ att_b,
    float* __restrict__ out)
{
    int g = blockIdx.x * 256 + threadIdx.x;
    int node = g >> 6;
    int lane = g & 63;
    int grp = lane >> 4;
    int sl = lane & 15;
    int cnt = deg[node * DEGS];
    if (cnt == 0) {
        if (grp < 2) {
            v4f z = {0.f, 0.f, 0.f, 0.f};
            __builtin_nontemporal_store(z, (v4f*)out + node * 32 + (grp ? 16 + sl : sl));
        }
        return;
    }
    int cc = (cnt < CAP) ? cnt : CAP;
    int trips = (cc + 3) >> 2;               // wave-uniform trip count
    int myoff = (lane < cc) ? slots[node * CAP + lane] : 0;

    // hd pairs {2sl,2sl+1} and {32+2sl,32+2sl+1} from hdu (bf16)
    uint2 ha = ((const uint2*)(hdu + (size_t)node * 64))[sl];
    uint2 hb = ((const uint2*)(hdu + (size_t)node * 64))[16 + sl];
    float2 hd01 = bf2f(ha.x), hd23 = bf2f(ha.y);
    float2 hd45 = bf2f(hb.x), hd67 = bf2f(hb.y);

    float4 aw0f = ((const float4*)att_w)[sl];
    float4 aw1f = ((const float4*)att_w)[16 + sl];
    float2 aw01 = make_float2(aw0f.x, aw0f.y), aw23 = make_float2(aw0f.z, aw0f.w);
    float2 aw45 = make_float2(aw1f.x, aw1f.y), aw67 = make_float2(aw1f.z, aw1f.w);
    float ab = att_b[0];
    float2 o01 = {0.f, 0.f}, o23 = {0.f, 0.f};
    float2 o45 = {0.f, 0.f}, o67 = {0.f, 0.f};
    float dsum = 0.f;
    #pragma unroll 4
    for (int t = 0; t < trips; ++t) {
        int i = 4 * t + grp;
        bool valid = (i < cc);
        int off = __shfl(myoff, valid ? i : 0);   // all lanes active here
        if (valid) {                              // row-uniform guard
            const uint4* hp = (const uint4*)(hx + off);
            uint4 qa = hp[sl];        // {h(2sl),x(2sl),h(2sl+1),x(2sl+1)} dense
            uint4 qb = hp[16 + sl];   // pairs 32+2sl, 32+2sl+1
            float2 p2 = {0.f, 0.f};
            p2 = pkfma(leaky2(pka(bf2f(qa.x), hd01)), aw01, p2);
            p2 = pkfma(leaky2(pka(bf2f(qa.z), hd23)), aw23, p2);
            p2 = pkfma(leaky2(pka(bf2f(qb.x), hd45)), aw45, p2);
            p2 = pkfma(leaky2(pka(bf2f(qb.z), hd67)), aw67, p2);
            float p = p2.x + p2.y;
            p = ROR_ADD(p, 0x128);       // row_ror:8  (row fully active)
            p = ROR_ADD(p, 0x124);       // row_ror:4
            p = ROR_ADD(p, 0x122);       // row_ror:2
            p = ROR_ADD(p, 0x121);       // row_ror:1
            float s = __expf(p + ab);
            float2 s2 = make_float2(s, s);
            o01 = pkfma(bf2f(qa.y), s2, o01);
            o23 = pkfma(bf2f(qa.w), s2, o23);
            o45 = pkfma(bf2f(qb.y), s2, o45);
            o67 = pkfma(bf2f(qb.w), s2, o67);
            dsum += s;
        }
    }
    dsum += __shfl_xor(dsum, 32);
    dsum += __shfl_xor(dsum, 16);
    #define XRED2(f) { f += __shfl_xor(f, 32); f += __shfl_xor(f, 16); }
    XRED2(o01.x) XRED2(o01.y) XRED2(o23.x) XRED2(o23.y)
    XRED2(o45.x) XRED2(o45.y) XRED2(o67.x) XRED2(o67.y)
    #undef XRED2
    float r = 1.0f / dsum;
    if (grp < 2) {
        v4f ov;
        if (grp == 0) {
            ov[0] = o01.x * r; ov[1] = o01.y * r; ov[2] = o23.x * r; ov[3] = o23.y * r;
            __builtin_nontemporal_store(ov, (v4f*)out + node * 32 + sl);
        } else {
            ov[0] = o45.x * r; ov[1] = o45.y * r; ov[2] = o67.x * r; ov[3] = o67.y * r;
            __builtin_nontemporal_store(ov, (v4f*)out + node * 32 + 16 + sl);
        }
    }
}

// ---------------------------------------------------------------------------
extern "C" void kernel_launch(void* const* d_in, const int* in_sizes, int n_in,
                              void* d_out, int out_size, void* d_ws, size_t ws_size,
                              hipStream_t stream)
{
    const float* x     = (const float*)d_in[0];
    const int*   src   = (const int*)d_in[1];
    const int*   dst   = (const int*)d_in[2];
    const float* src_w = (const float*)d_in[3];
    const float* src_b = (const float*)d_in[4];
    const float* dst_w = (const float*)d_in[5];
    const float* dst_b = (const float*)d_in[6];
    const float* att_w = (const float*)d_in[7];
    const float* att_b = (const float*)d_in[8];
    float* out = (float*)d_out;
    (void)in_sizes; (void)n_in; (void)out_size; (void)ws_size;

    // workspace layout (~71 MB)
    int* ws = (int*)d_ws;
    int* ideg  = ws;                              // 50,000 * DEGS = 1.6M ints
    int* slots = ws + 1600512;                    // 3,200,000 (16B aligned)
    unsigned* whT = (unsigned*)(ws + 4800512);    // 16,384 uints
    unsigned* yu  = whT + 16384;                  // 3.2M uints  (y bf16)
    uint2*    hx  = (uint2*)(yu + 3200000);       // 6.4M uints  (ha_s|x bf16)
    unsigned* hdu = (unsigned*)(ws + 4816896 + 3200000 + 6400000);  // 3.2M uints

    // prep: weight cvt + deg zero
    k_prepw<<<256, 256, 0, stream>>>(src_w, dst_w, whT, ideg);

    // standalone scatter: zero LDS, full occupancy for atomic parallelism
    k_scatter<<<SCAT_BLOCKS, 256, 0, stream>>>(src, dst, ideg, slots);

    // standalone GEMM: 1-wave blocks, 16 rows each, barrier-free
    k_gemm<<<GEMM_BLOCKS, 64, 0, stream>>>(x, whT, src_b, (unsigned*)hx, yu);

    // pass 1: neighbor mean -> hdu (bf16)
    k_mean<<<N_NODES * 64 / 256, 256, 0, stream>>>(
        yu, slots, ideg, dst_b, hdu);

    // pass 2: scores + softmax + weighted aggregation
    k_score<<<N_NODES * 64 / 256, 256, 0, stream>>>(
        hx, hdu, slots, ideg, att_w, att_b, out);
}

// Round 13
// 246.798 us; speedup vs baseline: 1.0415x; 1.0415x over previous
//
#include <hip/hip_runtime.h>
#include <math.h>

#define N_NODES 50000
#define N_EDGES 800000
#define DIM 128
#define NEG_SLOPE 0.01f
#define CAP 64    // per-node slot capacity; P(deg>64)~5e-15 for Poisson(16)
#define DEGS 32   // deg counter stride (ints): 1 counter per 128B line

#define GEMM_BLOCKS 3125   // 50000/16 rows, exact
#define SCAT_BLOCKS 3125   // 800000/256 edges, exact

typedef short v8s __attribute__((ext_vector_type(8)));
typedef float v4f __attribute__((ext_vector_type(4)));
typedef float v2f __attribute__((ext_vector_type(2)));

// ---- bf16 helpers (RNE) ---------------------------------------------------
__device__ inline unsigned f2bf2(float a, float b) {
    unsigned ua = __float_as_uint(a);
    unsigned ub = __float_as_uint(b);
    ua = (ua + 0x7fffu + ((ua >> 16) & 1u)) >> 16;
    ub = (ub + 0x7fffu + ((ub >> 16) & 1u)) & 0xffff0000u;
    return ua | ub;
}
// bf16 pair -> v2f (native vector so the backend can select v_pk_* f32 ops)
__device__ inline v2f bf2v(unsigned u) {
    v2f r;
    r.x = __uint_as_float(u << 16);
    r.y = __uint_as_float(u & 0xffff0000u);
    return r;
}
// leaky_relu(v) == max(v, slope*v) exactly, for 0 < slope < 1 (v_pk_mul+v_pk_max)
__device__ inline v2f lk2(v2f v) {
    return __builtin_elementwise_max(v, v * NEG_SLOPE);
}

// VALU-forwarded 16-lane sum via DPP row rotations. Executed only when the
// owning 16-lane row is fully active (validity is row-uniform).
#define ROR_ADD(v, CTRL) \
    ((v) + __int_as_float(__builtin_amdgcn_update_dpp( \
        0, __float_as_int(v), (CTRL), 0xf, 0xf, false)))

// ---------------------------------------------------------------------------
// Scatter + weight-prep merged: blocks 0-63 additionally convert the weights
// to whT bf16 (16384 entries == 64 blocks x 256 threads, exact). deg is
// zeroed by a hipMemsetAsync before this kernel. Zero LDS, 1 edge/thread,
// full occupancy ceiling -> maximal atomic parallelism.
// ---------------------------------------------------------------------------
__global__ __launch_bounds__(256) void k_scatter(
    const int* __restrict__ src, const int* __restrict__ dst,
    int* __restrict__ deg, int* __restrict__ slots,
    const float* __restrict__ src_w, const float* __restrict__ dst_w,
    unsigned* __restrict__ whT)
{
    int bx = blockIdx.x;
    int tid = threadIdx.x;
    if (bx < 64) {
        int gid = bx * 256 + tid;     // [0, 16384): whT[n][kk]
        int n = gid >> 6;
        int kk = gid & 63;
        const float* W = (n < 128) ? src_w : dst_w;
        int col = n & 127;
        float w0 = W[(2 * kk) * DIM + col];
        float w1 = W[(2 * kk + 1) * DIM + col];
        whT[gid] = f2bf2(w0, w1);
    }
    int e = bx * 256 + tid;           // exact: 3125*256 == 800000
    int s = src[e];
    int d = dst[e];
    int pos = atomicAdd(&deg[d * DEGS], 1);
    if (pos < CAP) slots[d * CAP + pos] = s * 64;
}

// ---------------------------------------------------------------------------
// Standalone GEMM, 1-wave blocks (16 rows each, exact tiling, barrier-free).
// ---------------------------------------------------------------------------
__global__ __launch_bounds__(64) void k_gemm(
    const float* __restrict__ x, const unsigned* __restrict__ whT,
    const float* __restrict__ src_b, unsigned* __restrict__ hx_u,
    unsigned* __restrict__ yu)
{
    __shared__ unsigned L[16][132];   // 8448 B; rows 16B-aligned, stride%32=4
    int bx = blockIdx.x;
    int lane = threadIdx.x;
    int quad = lane >> 4;
    int m = lane & 15;

    // ---- x staging loads (8 x float4; no guards, exact tiling) -------------
    int arow = bx * 16 + m;
    const float4* xp = (const float4*)(x + (size_t)arow * DIM + quad * 8);
    float4 f[4][2];
    #pragma unroll
    for (int k0 = 0; k0 < 4; ++k0) {
        f[k0][0] = xp[k0 * 8];
        f[k0][1] = xp[k0 * 8 + 1];
    }

    // ---- pack -> b[] + LDS -------------------------------------------------
    v8s b[4];
    #pragma unroll
    for (int k0 = 0; k0 < 4; ++k0) {
        union { unsigned u[4]; v8s s; } pk;
        pk.u[0] = f2bf2(f[k0][0].x, f[k0][0].y);
        pk.u[1] = f2bf2(f[k0][0].z, f[k0][0].w);
        pk.u[2] = f2bf2(f[k0][1].x, f[k0][1].y);
        pk.u[3] = f2bf2(f[k0][1].z, f[k0][1].w);
        b[k0] = pk.s;
        int c = k0 * 32 + quad * 8 + 1;          // x-pairs at odd columns
        L[m][c + 0] = pk.u[0];
        L[m][c + 2] = pk.u[1];
        L[m][c + 4] = pk.u[2];
        L[m][c + 6] = pk.u[3];
    }

    // ---- MFMA loop ---------------------------------------------------------
    v4f yacc[8];
    #pragma unroll
    for (int nt = 0; nt < 16; ++nt) {
        v4f acc = {0.f, 0.f, 0.f, 0.f};
        const uint4* ap = (const uint4*)(whT + (size_t)(nt * 16 + m) * 64 + quad * 4);
        #pragma unroll
        for (int k0 = 0; k0 < 4; ++k0) {
            union { uint4 u; v8s s; } af;
            af.u = ap[k0 * 4];
            acc = __builtin_amdgcn_mfma_f32_16x16x32_bf16(af.s, b[k0], acc, 0, 0, 0);
        }
        if (nt < 8) {                            // ha_src pairs at even cols
            float4 bia = ((const float4*)src_b)[nt * 4 + quad];
            int c = nt * 16 + quad * 4;
            L[m][c]     = f2bf2(acc[0] + bia.x, acc[1] + bia.y);
            L[m][c + 2] = f2bf2(acc[2] + bia.z, acc[3] + bia.w);
        } else {
            yacc[nt - 8] = acc;
        }
    }

    // ---- store hx (wave-private LDS; no barrier, no guards) ----------------
    int rbase0 = bx * 16;
    for (int i = lane; i < 512; i += 64) {
        int r = i >> 5, c = i & 31;
        ((uint4*)(hx_u + (size_t)(rbase0 + r) * 128))[c] = *(const uint4*)&L[r][c * 4];
    }

    // ---- stage yu into cols 0..63 of same buffer, store --------------------
    #pragma unroll
    for (int t = 0; t < 8; ++t) {
        int c = t * 8 + quad * 2;
        L[m][c]     = f2bf2(yacc[t][0], yacc[t][1]);
        L[m][c + 1] = f2bf2(yacc[t][2], yacc[t][3]);
    }
    for (int i = lane; i < 256; i += 64) {
        int r = i >> 4, c = i & 15;
        ((uint4*)(yu + (size_t)(rbase0 + r) * 64))[c] = *(const uint4*)&L[r][c * 4];
    }
}

// ---------------------------------------------------------------------------
// Fused mean + score + softmax + weighted agg (R11 structure, best measured)
// with the per-edge math rewritten on native float2 vectors so the backend
// emits packed VOP3P ops (v_pk_add/mul/max/fma_f32) -- ~40% fewer VALU ops
// per edge. Dense gathers: lane sl owns pairs {2sl,2sl+1},{32+2sl,32+2sl+1}.
// ---------------------------------------------------------------------------
__global__ __launch_bounds__(256) void k_fuse(
    const uint2* __restrict__ hx, const unsigned* __restrict__ yu,
    const int* __restrict__ slots, const int* __restrict__ deg,
    const float* __restrict__ dst_b, const float* __restrict__ att_w,
    const float* __restrict__ att_b, float* __restrict__ out)
{
    int g = blockIdx.x * 256 + threadIdx.x;
    int node = g >> 6;
    int lane = g & 63;
    int grp = lane >> 4;
    int sl = lane & 15;
    int cnt = deg[node * DEGS];
    if (cnt == 0) {
        if (grp < 2) {
            v4f z = {0.f, 0.f, 0.f, 0.f};
            __builtin_nontemporal_store(z, (v4f*)out + node * 32 + (grp ? 16 + sl : sl));
        }
        return;
    }
    int cc = (cnt < CAP) ? cnt : CAP;
    int trips = (cc + 3) >> 2;               // wave-uniform trip count
    int myoff = (lane < cc) ? slots[node * CAP + lane] : 0;

    // ---- pass 1: hd = mean(y[src]) + dst_b (packed adds) -------------------
    v2f hd01 = {0.f, 0.f}, hd23 = {0.f, 0.f};
    v2f hd45 = {0.f, 0.f}, hd67 = {0.f, 0.f};
    #pragma unroll 4
    for (int t = 0; t < trips; ++t) {
        int i = 4 * t + grp;
        bool valid = (i < cc);
        int off = __shfl(myoff, valid ? i : 0);   // all lanes active here
        if (valid) {                              // row-uniform guard
            const uint2* yp = (const uint2*)(yu + off);
            uint2 qa = yp[sl];        // y-pairs 2sl, 2sl+1 (dense per instr)
            uint2 qb = yp[16 + sl];   // y-pairs 32+2sl, 32+2sl+1
            hd01 += bf2v(qa.x);
            hd23 += bf2v(qa.y);
            hd45 += bf2v(qb.x);
            hd67 += bf2v(qb.y);
        }
    }
    float inv = 1.0f / (float)cnt;
    float m0 = hd01.x, m1 = hd01.y, m2 = hd23.x, m3 = hd23.y;
    float m4 = hd45.x, m5 = hd45.y, m6 = hd67.x, m7 = hd67.y;
    #define XRED(f) { f += __shfl_xor(f, 32); f += __shfl_xor(f, 16); f *= inv; }
    XRED(m0) XRED(m1) XRED(m2) XRED(m3) XRED(m4) XRED(m5) XRED(m6) XRED(m7)
    #undef XRED
    float4 db0 = ((const float4*)dst_b)[sl];        // feats 4sl..4sl+3
    float4 db1 = ((const float4*)dst_b)[16 + sl];   // feats 64+4sl..
    hd01 = (v2f){m0 + db0.x, m1 + db0.y};
    hd23 = (v2f){m2 + db0.z, m3 + db0.w};
    hd45 = (v2f){m4 + db1.x, m5 + db1.y};
    hd67 = (v2f){m6 + db1.z, m7 + db1.w};

    // ---- pass 2: scores + softmax + weighted sum (packed math) -------------
    float4 aw0f = ((const float4*)att_w)[sl];
    float4 aw1f = ((const float4*)att_w)[16 + sl];
    v2f aw01 = (v2f){aw0f.x, aw0f.y}, aw23 = (v2f){aw0f.z, aw0f.w};
    v2f aw45 = (v2f){aw1f.x, aw1f.y}, aw67 = (v2f){aw1f.z, aw1f.w};
    float ab = att_b[0];
    v2f o01 = {0.f, 0.f}, o23 = {0.f, 0.f};
    v2f o45 = {0.f, 0.f}, o67 = {0.f, 0.f};
    float dsum = 0.f;
    #pragma unroll 4
    for (int t = 0; t < trips; ++t) {
        int i = 4 * t + grp;
        bool valid = (i < cc);
        int off = __shfl(myoff, valid ? i : 0);   // all lanes active here
        if (valid) {                              // row-uniform guard
            const uint4* hp = (const uint4*)(hx + off);
            uint4 qa = hp[sl];        // {h(2sl),x(2sl),h(2sl+1),x(2sl+1)} dense
            uint4 qb = hp[16 + sl];   // pairs 32+2sl, 32+2sl+1
            v2f p2 = {0.f, 0.f};
            p2 = __builtin_elementwise_fma(lk2(bf2v(qa.x) + hd01), aw01, p2);
            p2 = __builtin_elementwise_fma(lk2(bf2v(qa.z) + hd23), aw23, p2);
            p2 = __builtin_elementwise_fma(lk2(bf2v(qb.x) + hd45), aw45, p2);
            p2 = __builtin_elementwise_fma(lk2(bf2v(qb.z) + hd67), aw67, p2);
            float p = p2.x + p2.y;
            p = ROR_ADD(p, 0x128);       // row_ror:8  (row fully active)
            p = ROR_ADD(p, 0x124);       // row_ror:4
            p = ROR_ADD(p, 0x122);       // row_ror:2
            p = ROR_ADD(p, 0x121);       // row_ror:1
            float s = __expf(p + ab);
            v2f s2 = (v2f){s, s};
            o01 = __builtin_elementwise_fma(bf2v(qa.y), s2, o01);
            o23 = __builtin_elementwise_fma(bf2v(qa.w), s2, o23);
            o45 = __builtin_elementwise_fma(bf2v(qb.y), s2, o45);
            o67 = __builtin_elementwise_fma(bf2v(qb.w), s2, o67);
            dsum += s;
        }
    }
    dsum += __shfl_xor(dsum, 32);
    dsum += __shfl_xor(dsum, 16);
    float r0 = o01.x, r1 = o01.y, r2 = o23.x, r3 = o23.y;
    float r4 = o45.x, r5 = o45.y, r6 = o67.x, r7 = o67.y;
    #define XRED2(f) { f += __shfl_xor(f, 32); f += __shfl_xor(f, 16); }
    XRED2(r0) XRED2(r1) XRED2(r2) XRED2(r3) XRED2(r4) XRED2(r5) XRED2(r6) XRED2(r7)
    #undef XRED2
    float r = 1.0f / dsum;
    if (grp < 2) {
        v4f ov;
        if (grp == 0) {      // feats 4sl..4sl+3 -> float4 index sl
            ov[0] = r0 * r; ov[1] = r1 * r; ov[2] = r2 * r; ov[3] = r3 * r;
            __builtin_nontemporal_store(ov, (v4f*)out + node * 32 + sl);
        } else {             // feats 64+4sl.. -> float4 index 16+sl
            ov[0] = r4 * r; ov[1] = r5 * r; ov[2] = r6 * r; ov[3] = r7 * r;
            __builtin_nontemporal_store(ov, (v4f*)out + node * 32 + 16 + sl);
        }
    }
}

// ---------------------------------------------------------------------------
extern "C" void kernel_launch(void* const* d_in, const int* in_sizes, int n_in,
                              void* d_out, int out_size, void* d_ws, size_t ws_size,
                              hipStream_t stream)
{
    const float* x     = (const float*)d_in[0];
    const int*   src   = (const int*)d_in[1];
    const int*   dst   = (const int*)d_in[2];
    const float* src_w = (const float*)d_in[3];
    const float* src_b = (const float*)d_in[4];
    const float* dst_w = (const float*)d_in[5];
    const float* dst_b = (const float*)d_in[6];
    const float* att_w = (const float*)d_in[7];
    const float* att_b = (const float*)d_in[8];
    float* out = (float*)d_out;
    (void)in_sizes; (void)n_in; (void)out_size; (void)ws_size;

    const size_t NF = (size_t)N_NODES * DIM;   // 6.4M

    // workspace layout (~58 MB)
    int* ws = (int*)d_ws;
    int* ideg  = ws;                              // 50,000 * DEGS = 1.6M ints
    int* slots = ws + 1600512;                    // 3,200,000 (16B aligned)
    unsigned* whT = (unsigned*)(ws + 4800512);    // 16,384 uints
    unsigned* yu  = whT + 16384;                  // 3.2M uints  (y bf16)
    uint2*    hx  = (uint2*)(yu + NF / 2);        // 3.2M uint2  (ha_s|x bf16)

    // zero the padded deg counters (graph-capture-safe memset node)
    hipMemsetAsync(ideg, 0, (size_t)N_NODES * DEGS * sizeof(int), stream);

    // scatter + weight-prep merged (prepw hidden under the atomic latency)
    k_scatter<<<SCAT_BLOCKS, 256, 0, stream>>>(
        src, dst, ideg, slots, src_w, dst_w, whT);

    // standalone GEMM: 1-wave blocks, 16 rows each, barrier-free
    k_gemm<<<GEMM_BLOCKS, 64, 0, stream>>>(x, whT, src_b, (unsigned*)hx, yu);

    // fused mean + score + softmax + weighted agg (packed-f32 math)
    k_fuse<<<N_NODES * 64 / 256, 256, 0, stream>>>(
        hx, yu, slots, ideg, dst_b, att_w, att_b, out);
}

// Round 14
// 242.017 us; speedup vs baseline: 1.0620x; 1.0198x over previous
//
#include <hip/hip_runtime.h>
#include <math.h>

#define N_NODES 50000
#define N_EDGES 800000
#define DIM 128
#define NEG_SLOPE 0.01f
#define CAP 64    // per-node slot capacity; P(deg>64)~5e-15 for Poisson(16)
#define DEGS 32   // deg counter stride (ints): 1 counter per 128B line

#define GEMM_BLOCKS 3125   // 50000/16 rows, exact
#define SCAT_BLOCKS 3125   // 800000/256 edges, exact (64 thr x 4 edges)
#define MERGED_BLOCKS (GEMM_BLOCKS + SCAT_BLOCKS)   // 6250, parity-interleaved

typedef short v8s __attribute__((ext_vector_type(8)));
typedef float v4f __attribute__((ext_vector_type(4)));
typedef float v2f __attribute__((ext_vector_type(2)));

// ---- bf16 helpers (RNE) ---------------------------------------------------
__device__ inline unsigned f2bf2(float a, float b) {
    unsigned ua = __float_as_uint(a);
    unsigned ub = __float_as_uint(b);
    ua = (ua + 0x7fffu + ((ua >> 16) & 1u)) >> 16;
    ub = (ub + 0x7fffu + ((ub >> 16) & 1u)) & 0xffff0000u;
    return ua | ub;
}
// bf16 pair -> v2f (native vector so the backend can select v_pk_* f32 ops)
__device__ inline v2f bf2v(unsigned u) {
    v2f r;
    r.x = __uint_as_float(u << 16);
    r.y = __uint_as_float(u & 0xffff0000u);
    return r;
}
// leaky_relu(v) == max(v, slope*v) exactly, for 0 < slope < 1
__device__ inline v2f lk2(v2f v) {
    return __builtin_elementwise_max(v, v * NEG_SLOPE);
}

// VALU-forwarded 16-lane sum via DPP row rotations. Executed only when the
// owning 16-lane row is fully active (validity is row-uniform).
#define ROR_ADD(v, CTRL) \
    ((v) + __int_as_float(__builtin_amdgcn_update_dpp( \
        0, __float_as_int(v), (CTRL), 0xf, 0xf, false)))

// ---------------------------------------------------------------------------
// Prep: weights -> whT bf16 (n-major, k-pair-contiguous) + zero deg counters
// (one word per 128B line). Must precede k_scatgemm (gemm role reads whT).
// ---------------------------------------------------------------------------
__global__ __launch_bounds__(256) void k_prepw(
    const float* __restrict__ src_w, const float* __restrict__ dst_w,
    unsigned* __restrict__ whT, int* __restrict__ deg)
{
    int gid = blockIdx.x * 256 + threadIdx.x;   // 256 blocks -> 65536 threads
    if (gid < 256 * 64) {
        int n = gid >> 6;
        int kk = gid & 63;
        const float* W = (n < 128) ? src_w : dst_w;
        int col = n & 127;
        float w0 = W[(2 * kk) * DIM + col];
        float w1 = W[(2 * kk + 1) * DIM + col];
        whT[gid] = f2bf2(w0, w1);
    }
    if (gid < N_NODES) deg[gid * DEGS] = 0;
}

// ---------------------------------------------------------------------------
// Scatter ∥ GEMM via parity-interleaved block roles in ONE dispatch:
//   odd  blocks -> scatter (64 thr x 4 edges; atomics only)
//   even blocks -> 1-wave GEMM (16 rows, 8.4 KB LDS, barrier-free)
// ~19 blocks/CU resident -> both roles co-scheduled on every CU for the
// whole kernel: atomic latency hides under MFMA/HBM work of gemm waves.
// Fixes the 3 prior merge failures: small LDS everywhere (not 50 KB),
// no phase drain (parity, not block-range split), no intra-wave
// serialization (roles in different waves).
// ---------------------------------------------------------------------------
__global__ __launch_bounds__(64) void k_scatgemm(
    const int* __restrict__ src, const int* __restrict__ dst,
    int* __restrict__ deg, int* __restrict__ slots,
    const float* __restrict__ x, const unsigned* __restrict__ whT,
    const float* __restrict__ src_b, unsigned* __restrict__ hx_u,
    unsigned* __restrict__ yu)
{
    __shared__ unsigned L[16][132];   // 8448 B; rows 16B-aligned, stride%32=4
    int b = blockIdx.x;
    int lane = threadIdx.x;

    if (b & 1) {
        // ---- scatter role: 256 edges, loads up front for MLP --------------
        int bs = b >> 1;
        int e0 = bs * 256 + lane;     // exact: 3125*256 == 800000
        int sv[4], dv[4], pos[4];
        #pragma unroll
        for (int i = 0; i < 4; ++i) {
            sv[i] = src[e0 + i * 64];
            dv[i] = dst[e0 + i * 64];
        }
        #pragma unroll
        for (int i = 0; i < 4; ++i)
            pos[i] = atomicAdd(&deg[dv[i] * DEGS], 1);
        #pragma unroll
        for (int i = 0; i < 4; ++i)
            if (pos[i] < CAP) slots[dv[i] * CAP + pos[i]] = sv[i] * 64;
        return;
    }

    // ---- GEMM role: rows bx*16 .. bx*16+15 --------------------------------
    int bx = b >> 1;
    int quad = lane >> 4;
    int m = lane & 15;

    int arow = bx * 16 + m;           // exact: 3125*16 == 50000
    const float4* xp = (const float4*)(x + (size_t)arow * DIM + quad * 8);
    float4 f[4][2];
    #pragma unroll
    for (int k0 = 0; k0 < 4; ++k0) {
        f[k0][0] = xp[k0 * 8];
        f[k0][1] = xp[k0 * 8 + 1];
    }

    v8s bb[4];
    #pragma unroll
    for (int k0 = 0; k0 < 4; ++k0) {
        union { unsigned u[4]; v8s s; } pk;
        pk.u[0] = f2bf2(f[k0][0].x, f[k0][0].y);
        pk.u[1] = f2bf2(f[k0][0].z, f[k0][0].w);
        pk.u[2] = f2bf2(f[k0][1].x, f[k0][1].y);
        pk.u[3] = f2bf2(f[k0][1].z, f[k0][1].w);
        bb[k0] = pk.s;
        int c = k0 * 32 + quad * 8 + 1;          // x-pairs at odd columns
        L[m][c + 0] = pk.u[0];
        L[m][c + 2] = pk.u[1];
        L[m][c + 4] = pk.u[2];
        L[m][c + 6] = pk.u[3];
    }

    v4f yacc[8];
    #pragma unroll
    for (int nt = 0; nt < 16; ++nt) {
        v4f acc = {0.f, 0.f, 0.f, 0.f};
        const uint4* ap = (const uint4*)(whT + (size_t)(nt * 16 + m) * 64 + quad * 4);
        #pragma unroll
        for (int k0 = 0; k0 < 4; ++k0) {
            union { uint4 u; v8s s; } af;
            af.u = ap[k0 * 4];
            acc = __builtin_amdgcn_mfma_f32_16x16x32_bf16(af.s, bb[k0], acc, 0, 0, 0);
        }
        if (nt < 8) {                            // ha_src pairs at even cols
            float4 bia = ((const float4*)src_b)[nt * 4 + quad];
            int c = nt * 16 + quad * 4;
            L[m][c]     = f2bf2(acc[0] + bia.x, acc[1] + bia.y);
            L[m][c + 2] = f2bf2(acc[2] + bia.z, acc[3] + bia.w);
        } else {
            yacc[nt - 8] = acc;
        }
    }

    int rbase0 = bx * 16;
    for (int i = lane; i < 512; i += 64) {
        int r = i >> 5, c = i & 31;
        ((uint4*)(hx_u + (size_t)(rbase0 + r) * 128))[c] = *(const uint4*)&L[r][c * 4];
    }

    #pragma unroll
    for (int t = 0; t < 8; ++t) {
        int c = t * 8 + quad * 2;
        L[m][c]     = f2bf2(yacc[t][0], yacc[t][1]);
        L[m][c + 1] = f2bf2(yacc[t][2], yacc[t][3]);
    }
    for (int i = lane; i < 256; i += 64) {
        int r = i >> 4, c = i & 15;
        ((uint4*)(yu + (size_t)(rbase0 + r) * 64))[c] = *(const uint4*)&L[r][c * 4];
    }
}

// ---------------------------------------------------------------------------
// Fused mean + score + softmax + weighted agg (R13 packed-f32 version).
// Dense gathers: lane sl owns pairs {2sl,2sl+1},{32+2sl,32+2sl+1}.
// ---------------------------------------------------------------------------
__global__ __launch_bounds__(256) void k_fuse(
    const uint2* __restrict__ hx, const unsigned* __restrict__ yu,
    const int* __restrict__ slots, const int* __restrict__ deg,
    const float* __restrict__ dst_b, const float* __restrict__ att_w,
    const float* __restrict__ att_b, float* __restrict__ out)
{
    int g = blockIdx.x * 256 + threadIdx.x;
    int node = g >> 6;
    int lane = g & 63;
    int grp = lane >> 4;
    int sl = lane & 15;
    int cnt = deg[node * DEGS];
    if (cnt == 0) {
        if (grp < 2) {
            v4f z = {0.f, 0.f, 0.f, 0.f};
            __builtin_nontemporal_store(z, (v4f*)out + node * 32 + (grp ? 16 + sl : sl));
        }
        return;
    }
    int cc = (cnt < CAP) ? cnt : CAP;
    int trips = (cc + 3) >> 2;               // wave-uniform trip count
    int myoff = (lane < cc) ? slots[node * CAP + lane] : 0;

    // ---- pass 1: hd = mean(y[src]) + dst_b (packed adds) -------------------
    v2f hd01 = {0.f, 0.f}, hd23 = {0.f, 0.f};
    v2f hd45 = {0.f, 0.f}, hd67 = {0.f, 0.f};
    #pragma unroll 4
    for (int t = 0; t < trips; ++t) {
        int i = 4 * t + grp;
        bool valid = (i < cc);
        int off = __shfl(myoff, valid ? i : 0);   // all lanes active here
        if (valid) {                              // row-uniform guard
            const uint2* yp = (const uint2*)(yu + off);
            uint2 qa = yp[sl];        // y-pairs 2sl, 2sl+1 (dense per instr)
            uint2 qb = yp[16 + sl];   // y-pairs 32+2sl, 32+2sl+1
            hd01 += bf2v(qa.x);
            hd23 += bf2v(qa.y);
            hd45 += bf2v(qb.x);
            hd67 += bf2v(qb.y);
        }
    }
    float inv = 1.0f / (float)cnt;
    float m0 = hd01.x, m1 = hd01.y, m2 = hd23.x, m3 = hd23.y;
    float m4 = hd45.x, m5 = hd45.y, m6 = hd67.x, m7 = hd67.y;
    #define XRED(f) { f += __shfl_xor(f, 32); f += __shfl_xor(f, 16); f *= inv; }
    XRED(m0) XRED(m1) XRED(m2) XRED(m3) XRED(m4) XRED(m5) XRED(m6) XRED(m7)
    #undef XRED
    float4 db0 = ((const float4*)dst_b)[sl];        // feats 4sl..4sl+3
    float4 db1 = ((const float4*)dst_b)[16 + sl];   // feats 64+4sl..
    hd01 = (v2f){m0 + db0.x, m1 + db0.y};
    hd23 = (v2f){m2 + db0.z, m3 + db0.w};
    hd45 = (v2f){m4 + db1.x, m5 + db1.y};
    hd67 = (v2f){m6 + db1.z, m7 + db1.w};

    // ---- pass 2: scores + softmax + weighted sum (packed math) -------------
    float4 aw0f = ((const float4*)att_w)[sl];
    float4 aw1f = ((const float4*)att_w)[16 + sl];
    v2f aw01 = (v2f){aw0f.x, aw0f.y}, aw23 = (v2f){aw0f.z, aw0f.w};
    v2f aw45 = (v2f){aw1f.x, aw1f.y}, aw67 = (v2f){aw1f.z, aw1f.w};
    float ab = att_b[0];
    v2f o01 = {0.f, 0.f}, o23 = {0.f, 0.f};
    v2f o45 = {0.f, 0.f}, o67 = {0.f, 0.f};
    float dsum = 0.f;
    #pragma unroll 4
    for (int t = 0; t < trips; ++t) {
        int i = 4 * t + grp;
        bool valid = (i < cc);
        int off = __shfl(myoff, valid ? i : 0);   // all lanes active here
        if (valid) {                              // row-uniform guard
            const uint4* hp = (const uint4*)(hx + off);
            uint4 qa = hp[sl];        // {h(2sl),x(2sl),h(2sl+1),x(2sl+1)} dense
            uint4 qb = hp[16 + sl];   // pairs 32+2sl, 32+2sl+1
            v2f p2 = {0.f, 0.f};
            p2 = __builtin_elementwise_fma(lk2(bf2v(qa.x) + hd01), aw01, p2);
            p2 = __builtin_elementwise_fma(lk2(bf2v(qa.z) + hd23), aw23, p2);
            p2 = __builtin_elementwise_fma(lk2(bf2v(qb.x) + hd45), aw45, p2);
            p2 = __builtin_elementwise_fma(lk2(bf2v(qb.z) + hd67), aw67, p2);
            float p = p2.x + p2.y;
            p = ROR_ADD(p, 0x128);       // row_ror:8  (row fully active)
            p = ROR_ADD(p, 0x124);       // row_ror:4
            p = ROR_ADD(p, 0x122);       // row_ror:2
            p = ROR_ADD(p, 0x121);       // row_ror:1
            float s = __expf(p + ab);
            v2f s2 = (v2f){s, s};
            o01 = __builtin_elementwise_fma(bf2v(qa.y), s2, o01);
            o23 = __builtin_elementwise_fma(bf2v(qa.w), s2, o23);
            o45 = __builtin_elementwise_fma(bf2v(qb.y), s2, o45);
            o67 = __builtin_elementwise_fma(bf2v(qb.w), s2, o67);
            dsum += s;
        }
    }
    dsum += __shfl_xor(dsum, 32);
    dsum += __shfl_xor(dsum, 16);
    float r0 = o01.x, r1 = o01.y, r2 = o23.x, r3 = o23.y;
    float r4 = o45.x, r5 = o45.y, r6 = o67.x, r7 = o67.y;
    #define XRED2(f) { f += __shfl_xor(f, 32); f += __shfl_xor(f, 16); }
    XRED2(r0) XRED2(r1) XRED2(r2) XRED2(r3) XRED2(r4) XRED2(r5) XRED2(r6) XRED2(r7)
    #undef XRED2
    float r = 1.0f / dsum;
    if (grp < 2) {
        v4f ov;
        if (grp == 0) {      // feats 4sl..4sl+3 -> float4 index sl
            ov[0] = r0 * r; ov[1] = r1 * r; ov[2] = r2 * r; ov[3] = r3 * r;
            __builtin_nontemporal_store(ov, (v4f*)out + node * 32 + sl);
        } else {             // feats 64+4sl.. -> float4 index 16+sl
            ov[0] = r4 * r; ov[1] = r5 * r; ov[2] = r6 * r; ov[3] = r7 * r;
            __builtin_nontemporal_store(ov, (v4f*)out + node * 32 + 16 + sl);
        }
    }
}

// ---------------------------------------------------------------------------
extern "C" void kernel_launch(void* const* d_in, const int* in_sizes, int n_in,
                              void* d_out, int out_size, void* d_ws, size_t ws_size,
                              hipStream_t stream)
{
    const float* x     = (const float*)d_in[0];
    const int*   src   = (const int*)d_in[1];
    const int*   dst   = (const int*)d_in[2];
    const float* src_w = (const float*)d_in[3];
    const float* src_b = (const float*)d_in[4];
    const float* dst_w = (const float*)d_in[5];
    const float* dst_b = (const float*)d_in[6];
    const float* att_w = (const float*)d_in[7];
    const float* att_b = (const float*)d_in[8];
    float* out = (float*)d_out;
    (void)in_sizes; (void)n_in; (void)out_size; (void)ws_size;

    const size_t NF = (size_t)N_NODES * DIM;   // 6.4M

    // workspace layout (~58 MB)
    int* ws = (int*)d_ws;
    int* ideg  = ws;                              // 50,000 * DEGS = 1.6M ints
    int* slots = ws + 1600512;                    // 3,200,000 (16B aligned)
    unsigned* whT = (unsigned*)(ws + 4800512);    // 16,384 uints
    unsigned* yu  = whT + 16384;                  // 3.2M uints  (y bf16)
    uint2*    hx  = (uint2*)(yu + NF / 2);        // 3.2M uint2  (ha_s|x bf16)

    // prep: weight cvt + deg zero (must precede scatgemm's gemm role)
    k_prepw<<<256, 256, 0, stream>>>(src_w, dst_w, whT, ideg);

    // scatter ∥ GEMM, parity-interleaved block roles, one dispatch
    k_scatgemm<<<MERGED_BLOCKS, 64, 0, stream>>>(
        src, dst, ideg, slots, x, whT, src_b, (unsigned*)hx, yu);

    // fused mean + score + softmax + weighted agg (packed-f32 math)
    k_fuse<<<N_NODES * 64 / 256, 256, 0, stream>>>(
        hx, yu, slots, ideg, dst_b, att_w, att_b, out);
}

// Round 15
// 236.060 us; speedup vs baseline: 1.0888x; 1.0252x over previous
//
#include <hip/hip_runtime.h>
#include <math.h>

#define N_NODES 50000
#define N_EDGES 800000
#define DIM 128
#define NEG_SLOPE 0.01f
#define CAP 64    // per-node slot capacity; P(deg>64)~5e-15 for Poisson(16)
#define DEGS 32   // deg counter stride (ints): 1 counter per 128B line

#define SG_BLOCKS 1042   // ceil(50000/48) rows; 1042*768 >= 800000 edges
#define ROWS_PB 48       // 3 gemm waves x 16 rows
#define EPB 768          // 1 scatter wave x 64 lanes x 12 edges

typedef short v8s __attribute__((ext_vector_type(8)));
typedef float v4f __attribute__((ext_vector_type(4)));
typedef float v2f __attribute__((ext_vector_type(2)));

// ---- bf16 helpers (RNE) ---------------------------------------------------
__device__ inline unsigned f2bf2(float a, float b) {
    unsigned ua = __float_as_uint(a);
    unsigned ub = __float_as_uint(b);
    ua = (ua + 0x7fffu + ((ua >> 16) & 1u)) >> 16;
    ub = (ub + 0x7fffu + ((ub >> 16) & 1u)) & 0xffff0000u;
    return ua | ub;
}
// bf16 pair -> v2f (native vector so the backend can select v_pk_* f32 ops)
__device__ inline v2f bf2v(unsigned u) {
    v2f r;
    r.x = __uint_as_float(u << 16);
    r.y = __uint_as_float(u & 0xffff0000u);
    return r;
}
// leaky_relu(v) == max(v, slope*v) exactly, for 0 < slope < 1
__device__ inline v2f lk2(v2f v) {
    return __builtin_elementwise_max(v, v * NEG_SLOPE);
}

// VALU-forwarded 16-lane sum via DPP row rotations. Executed only when the
// owning 16-lane row is fully active (validity is row-uniform).
#define ROR_ADD(v, CTRL) \
    ((v) + __int_as_float(__builtin_amdgcn_update_dpp( \
        0, __float_as_int(v), (CTRL), 0xf, 0xf, false)))

// ---------------------------------------------------------------------------
// Prep: weights -> whT bf16 (n-major, k-pair-contiguous) + zero deg counters
// (one word per 128B line). Must precede k_scatgemm (gemm waves read whT).
// ---------------------------------------------------------------------------
__global__ __launch_bounds__(256) void k_prepw(
    const float* __restrict__ src_w, const float* __restrict__ dst_w,
    unsigned* __restrict__ whT, int* __restrict__ deg)
{
    int gid = blockIdx.x * 256 + threadIdx.x;   // 256 blocks -> 65536 threads
    if (gid < 256 * 64) {
        int n = gid >> 6;
        int kk = gid & 63;
        const float* W = (n < 128) ? src_w : dst_w;
        int col = n & 127;
        float w0 = W[(2 * kk) * DIM + col];
        float w1 = W[(2 * kk + 1) * DIM + col];
        whT[gid] = f2bf2(w0, w1);
    }
    if (gid < N_NODES) deg[gid * DEGS] = 0;
}

// ---------------------------------------------------------------------------
// Scatter ∥ GEMM via intra-block wave roles: waves 0-2 = 16-row GEMM each
// (wave-private LDS slab, barrier-free), wave 3 = 768-edge scatter (12/lane,
// loads up front -> 12-deep atomic MLP). 25.3 KB LDS -> 6 blocks/CU =
// 24 waves/CU (~75% occupancy ceiling, 3x all prior merge attempts), and
// role mixing is guaranteed per-CU by construction. 18 gemm waves/CU hide
// the 6 scatter waves' atomic latency.
// ---------------------------------------------------------------------------
__global__ __launch_bounds__(256) void k_scatgemm(
    const int* __restrict__ src, const int* __restrict__ dst,
    int* __restrict__ deg, int* __restrict__ slots,
    const float* __restrict__ x, const unsigned* __restrict__ whT,
    const float* __restrict__ src_b, unsigned* __restrict__ hx_u,
    unsigned* __restrict__ yu)
{
    __shared__ unsigned L3[3][16][132];  // 25344 B; wave-private slabs
    int b = blockIdx.x;
    int tid = threadIdx.x;
    int wave = tid >> 6;
    int lane = tid & 63;

    if (wave == 3) {
        // ---- scatter role: 768 edges, loads first for deep MLP ------------
        int e0 = b * EPB + lane;
        int sv[12], dv[12], pos[12];
        #pragma unroll
        for (int i = 0; i < 12; ++i) {
            int e = e0 + i * 64;
            bool v = (e < N_EDGES);
            sv[i] = v ? src[e] : 0;
            dv[i] = v ? dst[e] : 0;
        }
        #pragma unroll
        for (int i = 0; i < 12; ++i) {
            int e = e0 + i * 64;
            pos[i] = (e < N_EDGES) ? atomicAdd(&deg[dv[i] * DEGS], 1) : CAP;
        }
        #pragma unroll
        for (int i = 0; i < 12; ++i)
            if (pos[i] < CAP) slots[dv[i] * CAP + pos[i]] = sv[i] * 64;
        return;
    }

    // ---- GEMM role: wave w owns rows b*48 + w*16 .. +15 -------------------
    unsigned (*L)[132] = L3[wave];
    int quad = lane >> 4;
    int m = lane & 15;
    int rbase0 = b * ROWS_PB + wave * 16;
    int arow = rbase0 + m;
    bool live = (arow < N_NODES);

    float4 f[4][2];
    #pragma unroll
    for (int k0 = 0; k0 < 4; ++k0) {
        f[k0][0] = make_float4(0.f, 0.f, 0.f, 0.f);
        f[k0][1] = f[k0][0];
    }
    if (live) {
        const float4* xp = (const float4*)(x + (size_t)arow * DIM + quad * 8);
        #pragma unroll
        for (int k0 = 0; k0 < 4; ++k0) {
            f[k0][0] = xp[k0 * 8];
            f[k0][1] = xp[k0 * 8 + 1];
        }
    }

    v8s bb[4];
    #pragma unroll
    for (int k0 = 0; k0 < 4; ++k0) {
        union { unsigned u[4]; v8s s; } pk;
        pk.u[0] = f2bf2(f[k0][0].x, f[k0][0].y);
        pk.u[1] = f2bf2(f[k0][0].z, f[k0][0].w);
        pk.u[2] = f2bf2(f[k0][1].x, f[k0][1].y);
        pk.u[3] = f2bf2(f[k0][1].z, f[k0][1].w);
        bb[k0] = pk.s;
        int c = k0 * 32 + quad * 8 + 1;          // x-pairs at odd columns
        L[m][c + 0] = pk.u[0];
        L[m][c + 2] = pk.u[1];
        L[m][c + 4] = pk.u[2];
        L[m][c + 6] = pk.u[3];
    }

    v4f yacc[8];
    #pragma unroll
    for (int nt = 0; nt < 16; ++nt) {
        v4f acc = {0.f, 0.f, 0.f, 0.f};
        const uint4* ap = (const uint4*)(whT + (size_t)(nt * 16 + m) * 64 + quad * 4);
        #pragma unroll
        for (int k0 = 0; k0 < 4; ++k0) {
            union { uint4 u; v8s s; } af;
            af.u = ap[k0 * 4];
            acc = __builtin_amdgcn_mfma_f32_16x16x32_bf16(af.s, bb[k0], acc, 0, 0, 0);
        }
        if (nt < 8) {                            // ha_src pairs at even cols
            float4 bia = ((const float4*)src_b)[nt * 4 + quad];
            int c = nt * 16 + quad * 4;
            L[m][c]     = f2bf2(acc[0] + bia.x, acc[1] + bia.y);
            L[m][c + 2] = f2bf2(acc[2] + bia.z, acc[3] + bia.w);
        } else {
            yacc[nt - 8] = acc;
        }
    }

    // ---- store hx (wave-private rows; no barrier) --------------------------
    for (int i = lane; i < 512; i += 64) {
        int r = i >> 5, c = i & 31;
        int row = rbase0 + r;
        if (row < N_NODES)
            ((uint4*)(hx_u + (size_t)row * 128))[c] = *(const uint4*)&L[r][c * 4];
    }

    // ---- stage yu into cols 0..63 of same slab, store ----------------------
    #pragma unroll
    for (int t = 0; t < 8; ++t) {
        int c = t * 8 + quad * 2;
        L[m][c]     = f2bf2(yacc[t][0], yacc[t][1]);
        L[m][c + 1] = f2bf2(yacc[t][2], yacc[t][3]);
    }
    for (int i = lane; i < 256; i += 64) {
        int r = i >> 4, c = i & 15;
        int row = rbase0 + r;
        if (row < N_NODES)
            ((uint4*)(yu + (size_t)row * 64))[c] = *(const uint4*)&L[r][c * 4];
    }
}

// ---------------------------------------------------------------------------
// Fused mean + score + softmax + weighted agg (R13 packed-f32 version).
// Dense gathers: lane sl owns pairs {2sl,2sl+1},{32+2sl,32+2sl+1}.
// ---------------------------------------------------------------------------
__global__ __launch_bounds__(256) void k_fuse(
    const uint2* __restrict__ hx, const unsigned* __restrict__ yu,
    const int* __restrict__ slots, const int* __restrict__ deg,
    const float* __restrict__ dst_b, const float* __restrict__ att_w,
    const float* __restrict__ att_b, float* __restrict__ out)
{
    int g = blockIdx.x * 256 + threadIdx.x;
    int node = g >> 6;
    int lane = g & 63;
    int grp = lane >> 4;
    int sl = lane & 15;
    int cnt = deg[node * DEGS];
    if (cnt == 0) {
        if (grp < 2) {
            v4f z = {0.f, 0.f, 0.f, 0.f};
            __builtin_nontemporal_store(z, (v4f*)out + node * 32 + (grp ? 16 + sl : sl));
        }
        return;
    }
    int cc = (cnt < CAP) ? cnt : CAP;
    int trips = (cc + 3) >> 2;               // wave-uniform trip count
    int myoff = (lane < cc) ? slots[node * CAP + lane] : 0;

    // ---- pass 1: hd = mean(y[src]) + dst_b (packed adds) -------------------
    v2f hd01 = {0.f, 0.f}, hd23 = {0.f, 0.f};
    v2f hd45 = {0.f, 0.f}, hd67 = {0.f, 0.f};
    #pragma unroll 4
    for (int t = 0; t < trips; ++t) {
        int i = 4 * t + grp;
        bool valid = (i < cc);
        int off = __shfl(myoff, valid ? i : 0);   // all lanes active here
        if (valid) {                              // row-uniform guard
            const uint2* yp = (const uint2*)(yu + off);
            uint2 qa = yp[sl];        // y-pairs 2sl, 2sl+1 (dense per instr)
            uint2 qb = yp[16 + sl];   // y-pairs 32+2sl, 32+2sl+1
            hd01 += bf2v(qa.x);
            hd23 += bf2v(qa.y);
            hd45 += bf2v(qb.x);
            hd67 += bf2v(qb.y);
        }
    }
    float inv = 1.0f / (float)cnt;
    float m0 = hd01.x, m1 = hd01.y, m2 = hd23.x, m3 = hd23.y;
    float m4 = hd45.x, m5 = hd45.y, m6 = hd67.x, m7 = hd67.y;
    #define XRED(f) { f += __shfl_xor(f, 32); f += __shfl_xor(f, 16); f *= inv; }
    XRED(m0) XRED(m1) XRED(m2) XRED(m3) XRED(m4) XRED(m5) XRED(m6) XRED(m7)
    #undef XRED
    float4 db0 = ((const float4*)dst_b)[sl];        // feats 4sl..4sl+3
    float4 db1 = ((const float4*)dst_b)[16 + sl];   // feats 64+4sl..
    hd01 = (v2f){m0 + db0.x, m1 + db0.y};
    hd23 = (v2f){m2 + db0.z, m3 + db0.w};
    hd45 = (v2f){m4 + db1.x, m5 + db1.y};
    hd67 = (v2f){m6 + db1.z, m7 + db1.w};

    // ---- pass 2: scores + softmax + weighted sum (packed math) -------------
    float4 aw0f = ((const float4*)att_w)[sl];
    float4 aw1f = ((const float4*)att_w)[16 + sl];
    v2f aw01 = (v2f){aw0f.x, aw0f.y}, aw23 = (v2f){aw0f.z, aw0f.w};
    v2f aw45 = (v2f){aw1f.x, aw1f.y}, aw67 = (v2f){aw1f.z, aw1f.w};
    float ab = att_b[0];
    v2f o01 = {0.f, 0.f}, o23 = {0.f, 0.f};
    v2f o45 = {0.f, 0.f}, o67 = {0.f, 0.f};
    float dsum = 0.f;
    #pragma unroll 4
    for (int t = 0; t < trips; ++t) {
        int i = 4 * t + grp;
        bool valid = (i < cc);
        int off = __shfl(myoff, valid ? i : 0);   // all lanes active here
        if (valid) {                              // row-uniform guard
            const uint4* hp = (const uint4*)(hx + off);
            uint4 qa = hp[sl];        // {h(2sl),x(2sl),h(2sl+1),x(2sl+1)} dense
            uint4 qb = hp[16 + sl];   // pairs 32+2sl, 32+2sl+1
            v2f p2 = {0.f, 0.f};
            p2 = __builtin_elementwise_fma(lk2(bf2v(qa.x) + hd01), aw01, p2);
            p2 = __builtin_elementwise_fma(lk2(bf2v(qa.z) + hd23), aw23, p2);
            p2 = __builtin_elementwise_fma(lk2(bf2v(qb.x) + hd45), aw45, p2);
            p2 = __builtin_elementwise_fma(lk2(bf2v(qb.z) + hd67), aw67, p2);
            float p = p2.x + p2.y;
            p = ROR_ADD(p, 0x128);       // row_ror:8  (row fully active)
            p = ROR_ADD(p, 0x124);       // row_ror:4
            p = ROR_ADD(p, 0x122);       // row_ror:2
            p = ROR_ADD(p, 0x121);       // row_ror:1
            float s = __expf(p + ab);
            v2f s2 = (v2f){s, s};
            o01 = __builtin_elementwise_fma(bf2v(qa.y), s2, o01);
            o23 = __builtin_elementwise_fma(bf2v(qa.w), s2, o23);
            o45 = __builtin_elementwise_fma(bf2v(qb.y), s2, o45);
            o67 = __builtin_elementwise_fma(bf2v(qb.w), s2, o67);
            dsum += s;
        }
    }
    dsum += __shfl_xor(dsum, 32);
    dsum += __shfl_xor(dsum, 16);
    float r0 = o01.x, r1 = o01.y, r2 = o23.x, r3 = o23.y;
    float r4 = o45.x, r5 = o45.y, r6 = o67.x, r7 = o67.y;
    #define XRED2(f) { f += __shfl_xor(f, 32); f += __shfl_xor(f, 16); }
    XRED2(r0) XRED2(r1) XRED2(r2) XRED2(r3) XRED2(r4) XRED2(r5) XRED2(r6) XRED2(r7)
    #undef XRED2
    float r = 1.0f / dsum;
    if (grp < 2) {
        v4f ov;
        if (grp == 0) {      // feats 4sl..4sl+3 -> float4 index sl
            ov[0] = r0 * r; ov[1] = r1 * r; ov[2] = r2 * r; ov[3] = r3 * r;
            __builtin_nontemporal_store(ov, (v4f*)out + node * 32 + sl);
        } else {             // feats 64+4sl.. -> float4 index 16+sl
            ov[0] = r4 * r; ov[1] = r5 * r; ov[2] = r6 * r; ov[3] = r7 * r;
            __builtin_nontemporal_store(ov, (v4f*)out + node * 32 + 16 + sl);
        }
    }
}

// ---------------------------------------------------------------------------
extern "C" void kernel_launch(void* const* d_in, const int* in_sizes, int n_in,
                              void* d_out, int out_size, void* d_ws, size_t ws_size,
                              hipStream_t stream)
{
    const float* x     = (const float*)d_in[0];
    const int*   src   = (const int*)d_in[1];
    const int*   dst   = (const int*)d_in[2];
    const float* src_w = (const float*)d_in[3];
    const float* src_b = (const float*)d_in[4];
    const float* dst_w = (const float*)d_in[5];
    const float* dst_b = (const float*)d_in[6];
    const float* att_w = (const float*)d_in[7];
    const float* att_b = (const float*)d_in[8];
    float* out = (float*)d_out;
    (void)in_sizes; (void)n_in; (void)out_size; (void)ws_size;

    const size_t NF = (size_t)N_NODES * DIM;   // 6.4M

    // workspace layout (~58 MB)
    int* ws = (int*)d_ws;
    int* ideg  = ws;                              // 50,000 * DEGS = 1.6M ints
    int* slots = ws + 1600512;                    // 3,200,000 (16B aligned)
    unsigned* whT = (unsigned*)(ws + 4800512);    // 16,384 uints
    unsigned* yu  = whT + 16384;                  // 3.2M uints  (y bf16)
    uint2*    hx  = (uint2*)(yu + NF / 2);        // 3.2M uint2  (ha_s|x bf16)

    // prep: weight cvt + deg zero (must precede scatgemm)
    k_prepw<<<256, 256, 0, stream>>>(src_w, dst_w, whT, ideg);

    // scatter ∥ GEMM: intra-block wave roles (3 gemm waves + 1 scatter wave)
    k_scatgemm<<<SG_BLOCKS, 256, 0, stream>>>(
        src, dst, ideg, slots, x, whT, src_b, (unsigned*)hx, yu);

    // fused mean + score + softmax + weighted agg (packed-f32 math)
    k_fuse<<<N_NODES * 64 / 256, 256, 0, stream>>>(
        hx, yu, slots, ideg, dst_b, att_w, att_b, out);
}